// Round 1
// baseline (17583.464 us; speedup 1.0000x reference)
//
#include <hip/hip_runtime.h>

#define SEQL 256
#define BATCH 64
#define HID 1024
#define NLAY 5
#define NBLK 64
#define NCLS 32000

typedef __attribute__((__ext_vector_type__(8))) short s16x8;
typedef __attribute__((__ext_vector_type__(4))) float f32x4;

__device__ __forceinline__ unsigned short f2bf(float f) {
  unsigned u = __float_as_uint(f);
  u = u + 0x7fffu + ((u >> 16) & 1u);
  return (unsigned short)(u >> 16);
}
__device__ __forceinline__ float bf2f(unsigned short s) {
  return __uint_as_float(((unsigned)s) << 16);
}
__device__ __forceinline__ float sigm(float x) { return 1.f / (1.f + __expf(-x)); }
__device__ __forceinline__ float tanh_f(float x) {
  float a = fabsf(x);
  float e = __expf(-2.f * a);
  float t = (1.f - e) / (1.f + e);
  return x < 0.f ? -t : t;
}

__device__ __forceinline__ void llds16(const void* g, void* l) {
  __builtin_amdgcn_global_load_lds((const __attribute__((address_space(1))) unsigned int*)g,
                                   (__attribute__((address_space(3))) unsigned int*)l,
                                   16, 0, 0);
}

// ---------------- weight packing: fp32 Wx/Wh -> bf16 MFMA-B fragments ----------------
// Wp index: ((((l*64 + j)*4 + g)*64 + k0)*64 + lane)*8 + i   (bf16 units)
// lane element i corresponds to  k = k0*32 + (lane>>4)*8 + i,  col h = j*16 + (lane&15)
// rows k<1024 come from Wx[l][g], rows >=1024 from Wh[l][g].
__global__ void pack_k(const float* __restrict__ Wx, const float* __restrict__ Wh,
                       unsigned short* __restrict__ Wp) {
  int bid = blockIdx.x;
  int k0 = bid & 63;
  int g = (bid >> 6) & 3;
  int j = (bid >> 8) & 63;
  int l = bid >> 14;
  int lane = threadIdx.x;
  int h = j * 16 + (lane & 15);
  int kb = k0 * 32 + (lane >> 4) * 8;
  const float* src;
  if (kb < 1024) src = Wx + ((size_t)((l * 4 + g) * 1024 + kb)) * 1024 + h;
  else           src = Wh + ((size_t)((l * 4 + g) * 1024 + (kb - 1024))) * 1024 + h;
  unsigned short o[8];
#pragma unroll
  for (int i = 0; i < 8; ++i) o[i] = f2bf(src[(size_t)i * 1024]);
  uint4 v;
  v.x = (unsigned)o[0] | ((unsigned)o[1] << 16);
  v.y = (unsigned)o[2] | ((unsigned)o[3] << 16);
  v.z = (unsigned)o[4] | ((unsigned)o[5] << 16);
  v.w = (unsigned)o[6] | ((unsigned)o[7] << 16);
  *(uint4*)(Wp + (((size_t)bid * 64 + lane) * 8)) = v;
}

// ---------------- embedding gather: x0[t][b][:] = bf16(emb[X[b][t]]) ----------------
__global__ void embed_k(const int* __restrict__ X, const float* __restrict__ emb,
                        unsigned short* __restrict__ hsA) {
  int sb = blockIdx.x;          // t*64 + b
  int t = sb >> 6, b = sb & 63;
  int row = X[b * SEQL + t];
  float4 v = ((const float4*)(emb + (size_t)row * HID))[threadIdx.x];
  unsigned short o0 = f2bf(v.x), o1 = f2bf(v.y), o2 = f2bf(v.z), o3 = f2bf(v.w);
  uint2 pk;
  pk.x = (unsigned)o0 | ((unsigned)o1 << 16);
  pk.y = (unsigned)o2 | ((unsigned)o3 << 16);
  ((uint2*)(hsA + (size_t)sb * HID))[threadIdx.x] = pk;
}

// ---------------- persistent fused LSTM ----------------
// 64 blocks x 256 threads. Block j owns hidden units [j*16, j*16+16) x 4 gates.
// Wave w computes gate w (64 rows x 16 cols), K = 2048 ([x_t ; h_{t-1}]).
// LDS: As (64 rows x 2048B, XOR-swizzled) | pre[4][64][17] f32 | c[64][16] f32
extern __shared__ char smem[];

__global__ void __launch_bounds__(256, 1)
lstm_pers(const unsigned short* __restrict__ Wp, const float* __restrict__ bias,
          unsigned short* hsA, unsigned short* hsB, int* flags) {
  const int j = blockIdx.x;
  const int tid = threadIdx.x;
  const int w = tid >> 6;
  const int lane = tid & 63;
  const int hl = lane & 15;
  const int ksub = lane >> 4;
  char* As = smem;                                   // 131072 B
  float* pre = (float*)(smem + 131072);              // 4*64*17 floats (padded)
  float* cst = (float*)(smem + 131072 + 17408);      // 64*16 floats

  const int sw = (hl & 7) << 4;  // row&7 == hl&7 for all row = m*16+hl

  for (int l = 0; l < NLAY; ++l) {
    const unsigned short* hin = (l & 1) ? hsB : hsA;
    unsigned short* hout = (l & 1) ? hsA : hsB;
    for (int q = tid; q < 1024; q += 256) cst[q] = 0.f;
    const unsigned short* wpL = Wp + (size_t)(l * 64 + j) * 131072 + (size_t)w * 32768;
    const float biasv = bias[(l * 4 + w) * 1024 + j * 16 + hl];

    for (int t = 0; t < SEQL; ++t) {
      // ---- stage x_t into LDS (swizzled via pre-permuted global source) ----
      {
        const char* src = (const char*)(hin + (size_t)t * BATCH * HID);
#pragma unroll
        for (int it = 0; it < 32; ++it) {
          int q = it * 4 + w;
          int row = q >> 1;
          int ob = (q & 1) * 64;
          int sidx = (ob + lane) ^ (row & 7);
          llds16(src + row * 2048 + sidx * 16, As + row * 2048 + ob * 16);
        }
      }
      __syncthreads();

      f32x4 acc[4];
#pragma unroll
      for (int m = 0; m < 4; ++m) acc[m] = (f32x4){0.f, 0.f, 0.f, 0.f};

      // ---- K over x (k0 = 0..31) ----
      {
        const unsigned short* wp = wpL;
#pragma unroll 4
        for (int k0 = 0; k0 < 32; ++k0) {
          s16x8 bv = *(const s16x8*)(wp + (size_t)k0 * 512 + lane * 8);
          int xo = (k0 * 64 + ksub * 16) ^ sw;
#pragma unroll
          for (int m = 0; m < 4; ++m) {
            s16x8 av = *(const s16x8*)(As + (m * 16 + hl) * 2048 + xo);
            acc[m] = __builtin_amdgcn_mfma_f32_16x16x32_bf16(av, bv, acc[m], 0, 0, 0);
          }
        }
      }

      // ---- K over h_{t-1} (k0 = 32..63), skipped at t==0 (h0 == 0) ----
      if (t > 0) {
        __syncthreads();
        const char* src = (const char*)(hout + (size_t)(t - 1) * BATCH * HID);
#pragma unroll
        for (int it = 0; it < 32; ++it) {
          int q = it * 4 + w;
          int row = q >> 1;
          int ob = (q & 1) * 64;
          int sidx = (ob + lane) ^ (row & 7);
          llds16(src + row * 2048 + sidx * 16, As + row * 2048 + ob * 16);
        }
        __syncthreads();
        const unsigned short* wp = wpL + 32 * 512;
#pragma unroll 4
        for (int k0 = 0; k0 < 32; ++k0) {
          s16x8 bv = *(const s16x8*)(wp + (size_t)k0 * 512 + lane * 8);
          int xo = (k0 * 64 + ksub * 16) ^ sw;
#pragma unroll
          for (int m = 0; m < 4; ++m) {
            s16x8 av = *(const s16x8*)(As + (m * 16 + hl) * 2048 + xo);
            acc[m] = __builtin_amdgcn_mfma_f32_16x16x32_bf16(av, bv, acc[m], 0, 0, 0);
          }
        }
      }

      // ---- epilogue: pre = acc + bias -> LDS ----
#pragma unroll
      for (int m = 0; m < 4; ++m)
#pragma unroll
        for (int r = 0; r < 4; ++r) {
          int row = m * 16 + ksub * 4 + r;
          pre[(w * 64 + row) * 17 + hl] = acc[m][r] + biasv;
        }
      __syncthreads();

      // ---- gates (fp32), c-state in LDS, write h (bf16) ----
      {
        int b = tid >> 2;
        int h0 = (tid & 3) * 4;
        unsigned short hw[4];
#pragma unroll
        for (int qq = 0; qq < 4; ++qq) {
          int hh = h0 + qq;
          float pi = pre[(0 * 64 + b) * 17 + hh];
          float pf = pre[(1 * 64 + b) * 17 + hh];
          float po = pre[(2 * 64 + b) * 17 + hh];
          float pg = pre[(3 * 64 + b) * 17 + hh];
          float iv = sigm(pi), fv = sigm(pf), ov = sigm(po), gv = tanh_f(pg);
          float c = fv * cst[b * 16 + hh] + iv * gv;
          cst[b * 16 + hh] = c;
          hw[qq] = f2bf(ov * tanh_f(c));
        }
        uint2 pk;
        pk.x = (unsigned)hw[0] | ((unsigned)hw[1] << 16);
        pk.y = (unsigned)hw[2] | ((unsigned)hw[3] << 16);
        *(uint2*)(hout + (size_t)(t * 64 + b) * HID + j * 16 + h0) = pk;
      }
      __syncthreads();

      // ---- device-scope step barrier (all 64 blocks) ----
      int id = l * 256 + t + 1;
      if (tid == 0) {
        __threadfence();
        __hip_atomic_store(&flags[j * 16], id, __ATOMIC_RELEASE, __HIP_MEMORY_SCOPE_AGENT);
      }
      if (w == 0) {
        for (;;) {
          int v = __hip_atomic_load(&flags[lane * 16], __ATOMIC_RELAXED, __HIP_MEMORY_SCOPE_AGENT);
          if (__all(v >= id)) break;
          __builtin_amdgcn_s_sleep(8);
        }
        __threadfence();
      }
      __syncthreads();
    }
  }
}

// ---------------- output projection (fp32, K split 2-way) ----------------
__global__ void __launch_bounds__(256) proj_k(const unsigned short* __restrict__ hlast,
                                              const float* __restrict__ Whq,
                                              float* __restrict__ part) {
  __shared__ float hlds[64 * 128];
  int kh = blockIdx.x / 125;
  int nb = blockIdx.x % 125;
  int n = nb * 256 + threadIdx.x;
  float acc[64];
#pragma unroll
  for (int b = 0; b < 64; ++b) acc[b] = 0.f;
  for (int kc = 0; kc < 4; ++kc) {
    int kbase = kh * 512 + kc * 128;
    __syncthreads();
#pragma unroll
    for (int it = 0; it < 32; ++it) {
      int id = threadIdx.x + it * 256;
      int b = id >> 7, k = id & 127;
      hlds[b * 128 + k] = bf2f(hlast[(size_t)b * HID + kbase + k]);
    }
    __syncthreads();
    for (int k4 = 0; k4 < 32; ++k4) {
      float w0 = Whq[(size_t)(kbase + k4 * 4 + 0) * NCLS + n];
      float w1 = Whq[(size_t)(kbase + k4 * 4 + 1) * NCLS + n];
      float w2 = Whq[(size_t)(kbase + k4 * 4 + 2) * NCLS + n];
      float w3 = Whq[(size_t)(kbase + k4 * 4 + 3) * NCLS + n];
#pragma unroll
      for (int b = 0; b < 64; ++b) {
        float4 h4 = *(const float4*)&hlds[b * 128 + k4 * 4];
        acc[b] += h4.x * w0 + h4.y * w1 + h4.z * w2 + h4.w * w3;
      }
    }
  }
#pragma unroll
  for (int b = 0; b < 64; ++b)
    part[(size_t)kh * 64 * NCLS + (size_t)b * NCLS + n] = acc[b];
}

__global__ void combine_k(const float* __restrict__ part, const float* __restrict__ bq,
                          float* __restrict__ out) {
  int i = blockIdx.x * 256 + threadIdx.x;
  int n = i % NCLS;
  out[i] = part[i] + part[64 * NCLS + i] + bq[n];
}

extern "C" void kernel_launch(void* const* d_in, const int* in_sizes, int n_in,
                              void* d_out, int out_size, void* d_ws, size_t ws_size,
                              hipStream_t stream) {
  const int* X = (const int*)d_in[0];
  const float* emb = (const float*)d_in[1];
  const float* Wx = (const float*)d_in[2];
  const float* Wh = (const float*)d_in[3];
  const float* bias = (const float*)d_in[4];
  const float* Whq = (const float*)d_in[5];
  const float* bq = (const float*)d_in[6];
  float* out = (float*)d_out;
  char* ws = (char*)d_ws;

  // ws layout (bytes)
  const size_t WP_OFF = 0;                         // 83,886,080  packed weights bf16
  const size_t HSA_OFF = 83886080;                 // 33,554,432  hs ping
  const size_t HSB_OFF = HSA_OFF + 33554432;       // 33,554,432  hs pong
  const size_t PART_OFF = HSB_OFF + 33554432;      // 16,384,000  proj partials
  const size_t FLAG_OFF = PART_OFF + 16384000;     // 4,096       barrier flags
  const size_t NEED = FLAG_OFF + 4096;
  if (ws_size < NEED) return;  // insufficient scratch: bail (deterministic)

  unsigned short* Wp = (unsigned short*)(ws + WP_OFF);
  unsigned short* hsA = (unsigned short*)(ws + HSA_OFF);
  unsigned short* hsB = (unsigned short*)(ws + HSB_OFF);
  float* part = (float*)(ws + PART_OFF);
  int* flags = (int*)(ws + FLAG_OFF);

  hipMemsetAsync(flags, 0, 64 * 16 * sizeof(int), stream);
  pack_k<<<81920, 64, 0, stream>>>(Wx, Wh, Wp);
  embed_k<<<16384, 256, 0, stream>>>(X, emb, hsA);
  (void)hipFuncSetAttribute(reinterpret_cast<const void*>(&lstm_pers),
                            hipFuncAttributeMaxDynamicSharedMemorySize, 152576);
  lstm_pers<<<NBLK, 256, 152576, stream>>>(Wp, bias, hsA, hsB, flags);
  const unsigned short* hlastp = hsB + (size_t)255 * BATCH * HID;  // layer 4 output, t=255
  proj_k<<<250, 256, 0, stream>>>(hlastp, Whq, part);
  combine_k<<<8000, 256, 0, stream>>>(part, bq, out);
}